// Round 7
// baseline (118.944 us; speedup 1.0000x reference)
//
#include <hip/hip_runtime.h>

typedef short bf16x8 __attribute__((ext_vector_type(8)));
typedef float f32x4 __attribute__((ext_vector_type(4)));

#define NTOK 262144
#define HH 100
#define DW 100
#define DT 25
#define KK 125

__device__ __forceinline__ short f2bf(float f) {
    union { float f; unsigned u; } v; v.f = f;
    unsigned u = v.u + 0x7FFFu + ((v.u >> 16) & 1u);   // RNE bf16 (inputs finite)
    return (short)(u >> 16);
}

__device__ __forceinline__ float sigm(float x) {
    return __builtin_amdgcn_rcpf(1.f + __expf(-x));
}
__device__ __forceinline__ float tanh_(float x) {
    return 2.f * __builtin_amdgcn_rcpf(1.f + __expf(-2.f * x)) - 1.f;
}

// ---------------- pre-kernel: build B fragments + folded biases in ws ----------------
// bfrag layout: [p(14 = d*7+jt)][fid(12 = gt*4+ks)][lane(64)] bf16x8  (= 172032 B)
// bias3 layout: [d(2)][gt(3)][jpad(112)] float                        (= 2688 B)
__global__ __launch_bounds__(256)
void build_b(const float* __restrict__ Wf, const float* __restrict__ bif, const float* __restrict__ bhf,
             const float* __restrict__ Wb, const float* __restrict__ bib, const float* __restrict__ bhb,
             bf16x8* __restrict__ bfrag, float* __restrict__ bias3)
{
    const int gwid = (blockIdx.x * 256 + threadIdx.x) >> 6;   // 0..167
    const int lane = threadIdx.x & 63;
    if (gwid >= 168) return;
    const int d   = gwid / 84;
    const int rem = gwid % 84;           // jt*12 + fid
    const int jt  = rem / 12, fid = rem % 12;
    const int gt  = fid >> 2, ks = fid & 3;
    const int l15 = lane & 15, lg = lane >> 4;
    const int j = jt * 16 + l15;
    const bool jv = (j < HH);
    const float* W = d ? Wb : Wf;
    const int gbase = (gt == 0) ? 0 : (gt == 1) ? 2 * HH : 3 * HH;   // i, g, o (f dead: c0==0)
    const float* wrow = W + (size_t)(gbase + (jv ? j : 0)) * KK;
    bf16x8 f;
    #pragma unroll
    for (int e = 0; e < 8; ++e) {
        const int k = ks * 32 + lg * 8 + e;
        const float v = (jv && k < KK) ? wrow[k] : 0.f;
        f[e] = f2bf(v);
    }
    bfrag[(size_t)gwid * 64 + lane] = f;
    if (ks == 0 && lg == 0) {
        const float* bi = d ? bib : bif;
        const float* bh = d ? bhb : bhf;
        bias3[(d * 3 + gt) * 112 + jt * 16 + l15] =
            jv ? (bi[gbase + j] + bh[gbase + j]) : 0.f;
    }
}

// ---------------- main kernel ----------------
// 4 waves x 32 tokens per block (128 tokens), grid 2048.
// W slab per (d,jt) phase staged in double-buffered LDS, shared by all 4 waves
// (fixes round-6's per-wave L2 re-reads: 168 KB/wave -> 168 KB/block on TA pipe).
// T14 split: next phase's 3 global loads issued at phase top, ds_write after
// compute; ONE barrier per phase (dbuf). Dense per-wave hstage flush retained.
__global__ __launch_bounds__(256, 2)
void lstm_main(const int* __restrict__ sent, const int* __restrict__ tags,
               const float* __restrict__ Ew, const float* __restrict__ Et,
               const bf16x8* __restrict__ bfrag, const float* __restrict__ bias3,
               float* __restrict__ out)
{
    __shared__ bf16x8 wbuf[2 * 12 * 64];    // 24576 B: [buf][fid][lane]
    __shared__ float hstage[4][32 * 100];   // 51200 B: per-wave private
    const int tid  = threadIdx.x;
    const int lane = tid & 63;
    const int wave = tid >> 6;
    const int l15  = lane & 15;        // token within 16-tile
    const int lg   = lane >> 4;        // k-group (inputs) / j-quad (output)
    const int kb0  = lg * 8;
    const int tok_base = blockIdx.x * 128 + wave * 32;

    // ---- gather x fragments (MFMA B-operand): x = [E_w row | E_t row | pad] ----
    bf16x8 a[2][4];
    #pragma unroll
    for (int mt = 0; mt < 2; ++mt) {
        const int tok = tok_base + mt * 16 + l15;
        const float* ew = Ew + (size_t)sent[tok] * DW;
        const float* et = Et + (size_t)tags[tok] * DT;
        #pragma unroll
        for (int ks = 0; ks < 3; ++ks) {          // k in [0,96): pure E_w, 16B-aligned
            const float* p = ew + ks * 32 + kb0;
            const float4 v0 = *(const float4*)p;
            const float4 v1 = *(const float4*)(p + 4);
            bf16x8 f;
            f[0] = f2bf(v0.x); f[1] = f2bf(v0.y); f[2] = f2bf(v0.z); f[3] = f2bf(v0.w);
            f[4] = f2bf(v1.x); f[5] = f2bf(v1.y); f[6] = f2bf(v1.z); f[7] = f2bf(v1.w);
            a[mt][ks] = f;
        }
        {   // ks == 3: k in [96,128) -> E_w tail / E_t / zero pad
            float v[8];
            if (lg == 0) {
                const float4 w = *(const float4*)(ew + 96);
                v[0] = w.x; v[1] = w.y; v[2] = w.z; v[3] = w.w;
                #pragma unroll
                for (int e = 0; e < 4; ++e) v[4 + e] = et[e];
            } else {
                const int base = lg * 8 - 4;       // E_t index of elem 0
                #pragma unroll
                for (int e = 0; e < 8; ++e) {
                    const int ti = base + e;
                    v[e] = (ti < DT) ? et[ti] : 0.f;
                }
            }
            bf16x8 f;
            #pragma unroll
            for (int e = 0; e < 8; ++e) f[e] = f2bf(v[e]);
            a[mt][3] = f;
        }
    }

    float* hs = hstage[wave];

    // prologue: stage phase 0 into buf 0
    bf16x8 st[3];
    {
        const bf16x8* bp = bfrag + (size_t)(wave * 3) * 64 + lane;
        st[0] = bp[0]; st[1] = bp[64]; st[2] = bp[128];
        #pragma unroll
        for (int q = 0; q < 3; ++q)
            wbuf[(wave * 3 + q) * 64 + lane] = st[q];
    }

    for (int d = 0; d < 2; ++d) {
        for (int jt = 0; jt < 7; ++jt) {
            const int p   = d * 7 + jt;
            const int cur = p & 1;
            __syncthreads();   // buf[cur] writes visible; buf[cur^1] readers done

            // issue next phase's global loads early (hide L2 latency under compute)
            if (p < 13) {
                const bf16x8* bp = bfrag + ((size_t)(p + 1) * 12 + wave * 3) * 64 + lane;
                st[0] = bp[0]; st[1] = bp[64]; st[2] = bp[128];
            }

            f32x4 acc[2][3];
            #pragma unroll
            for (int gt = 0; gt < 3; ++gt) {
                // bias pre-folded into accumulator init (row = j = jt*16+lg*4+r)
                const f32x4 bv = *(const f32x4*)&bias3[(size_t)(d * 3 + gt) * 112 + jt * 16 + lg * 4];
                acc[0][gt] = bv;
                acc[1][gt] = bv;
                bf16x8 b[4];
                #pragma unroll
                for (int ks = 0; ks < 4; ++ks)
                    b[ks] = wbuf[(cur * 12 + gt * 4 + ks) * 64 + lane];
                #pragma unroll
                for (int mt = 0; mt < 2; ++mt)
                    #pragma unroll
                    for (int ks = 0; ks < 4; ++ks)
                        acc[mt][gt] = __builtin_amdgcn_mfma_f32_16x16x32_bf16(
                            b[ks], a[mt][ks], acc[mt][gt], 0, 0, 0);
            }

            const bool sv = (jt < 6) || (lg == 0);   // j-quad valid (j<100)
            if (sv) {
                #pragma unroll
                for (int mt = 0; mt < 2; ++mt) {
                    f32x4 h;
                    #pragma unroll
                    for (int r = 0; r < 4; ++r) {
                        const float c = sigm(acc[mt][0][r]) * tanh_(acc[mt][1][r]);
                        h[r] = sigm(acc[mt][2][r]) * tanh_(c);
                    }
                    // packed staging: [token(32)][j(100)] f32
                    *(f32x4*)&hs[(mt * 16 + l15) * 100 + jt * 16 + lg * 4] = h;
                }
            }

            if (jt == 6) {
                // dense flush of this direction: 32 tokens x 400B, ~1KB/wave-store
                float* dst = out + (size_t)tok_base * 200 + d * 100;
                #pragma unroll
                for (int it = 0; it < 13; ++it) {
                    const int fd = it * 256 + lane * 4;     // dword offset, packed space
                    if (fd < 3200) {
                        const int t = fd / 100;             // token (magic-mul)
                        const f32x4 v = *(const f32x4*)&hs[fd];
                        *(f32x4*)&dst[fd + t * 100] = v;    // = dst[t*200 + (fd - t*100)]
                    }
                }
            }

            // late ds_write of next phase's slab into the other buffer
            if (p < 13) {
                const int nxt = cur ^ 1;
                #pragma unroll
                for (int q = 0; q < 3; ++q)
                    wbuf[(nxt * 12 + wave * 3 + q) * 64 + lane] = st[q];
            }
        }
    }
}

extern "C" void kernel_launch(void* const* d_in, const int* in_sizes, int n_in,
                              void* d_out, int out_size, void* d_ws, size_t ws_size,
                              hipStream_t stream) {
    (void)in_sizes; (void)n_in; (void)out_size; (void)ws_size;
    bf16x8* bfrag = (bf16x8*)d_ws;                       // 172032 B
    float*  bias3 = (float*)((char*)d_ws + 172032);      // 2688 B
    build_b<<<dim3(42), dim3(256), 0, stream>>>(
        (const float*)d_in[4], (const float*)d_in[5], (const float*)d_in[6],
        (const float*)d_in[7], (const float*)d_in[8], (const float*)d_in[9],
        bfrag, bias3);
    lstm_main<<<dim3(NTOK / 128), dim3(256), 0, stream>>>(
        (const int*)d_in[0], (const int*)d_in[1],
        (const float*)d_in[2], (const float*)d_in[3],
        bfrag, bias3, (float*)d_out);
}

// Round 8
// 112.350 us; speedup vs baseline: 1.0587x; 1.0587x over previous
//
#include <hip/hip_runtime.h>

typedef short bf16x8 __attribute__((ext_vector_type(8)));
typedef float f32x4 __attribute__((ext_vector_type(4)));

#define NTOK 262144
#define HH 100
#define DW 100
#define DT 25
#define KK 125

__device__ __forceinline__ short f2bf(float f) {
    union { float f; unsigned u; } v; v.f = f;
    unsigned u = v.u + 0x7FFFu + ((v.u >> 16) & 1u);   // RNE bf16 (inputs finite)
    return (short)(u >> 16);
}

__device__ __forceinline__ float sigm(float x) {
    return __builtin_amdgcn_rcpf(1.f + __expf(-x));
}
__device__ __forceinline__ float tanh_(float x) {
    return 2.f * __builtin_amdgcn_rcpf(1.f + __expf(-2.f * x)) - 1.f;
}

// ---------------- pre-kernel: build B fragments + folded biases in ws ----------------
// bfrag layout: [sid(14 = d*7+jt)][fid(12 = gt*4+ks)][lane(64)] bf16x8  (= 172032 B)
// bias3 layout: [d(2)][gt(3)][jpad(112)] float                          (= 2688 B)
__global__ __launch_bounds__(256)
void build_b(const float* __restrict__ Wf, const float* __restrict__ bif, const float* __restrict__ bhf,
             const float* __restrict__ Wb, const float* __restrict__ bib, const float* __restrict__ bhb,
             bf16x8* __restrict__ bfrag, float* __restrict__ bias3)
{
    const int gwid = (blockIdx.x * 256 + threadIdx.x) >> 6;   // 0..167
    const int lane = threadIdx.x & 63;
    if (gwid >= 168) return;
    const int d   = gwid / 84;
    const int rem = gwid % 84;           // jt*12 + fid
    const int jt  = rem / 12, fid = rem % 12;
    const int gt  = fid >> 2, ks = fid & 3;
    const int l15 = lane & 15, lg = lane >> 4;
    const int j = jt * 16 + l15;
    const bool jv = (j < HH);
    const float* W = d ? Wb : Wf;
    const int gbase = (gt == 0) ? 0 : (gt == 1) ? 2 * HH : 3 * HH;   // i, g, o (f dead: c0==0)
    const float* wrow = W + (size_t)(gbase + (jv ? j : 0)) * KK;
    bf16x8 f;
    #pragma unroll
    for (int e = 0; e < 8; ++e) {
        const int k = ks * 32 + lg * 8 + e;
        const float v = (jv && k < KK) ? wrow[k] : 0.f;
        f[e] = f2bf(v);
    }
    bfrag[(size_t)gwid * 64 + lane] = f;
    if (ks == 0 && lg == 0) {
        const float* bi = d ? bib : bif;
        const float* bh = d ? bhb : bhf;
        bias3[(d * 3 + gt) * 112 + jt * 16 + l15] =
            jv ? (bi[gbase + j] + bh[gbase + j]) : 0.f;
    }
}

// ---------------- main kernel ----------------
// 4 waves x 32 tokens per block (128 tokens), grid 2048.
// LDS budget 37.9 KB -> 4 blocks/CU (16 waves/CU): single-buffered W slab
// (12.3 KB) with T14 register prefetch of the next slab, + per-wave 16-token
// hstage (6.4 KB/wave) via mt-outer loop (28 short phases). Dense per-token
// 400B flush keeps WRITE_SIZE at ~1.05x ideal (confirmed R7: 224 MB).
__global__ __launch_bounds__(256, 4)
void lstm_main(const int* __restrict__ sent, const int* __restrict__ tags,
               const float* __restrict__ Ew, const float* __restrict__ Et,
               const bf16x8* __restrict__ bfrag, const float* __restrict__ bias3,
               float* __restrict__ out)
{
    __shared__ bf16x8 wbuf[12 * 64];        // 12288 B: [fid][lane]
    __shared__ float hstage[4][16 * 100];   // 25600 B: per-wave private
    const int tid  = threadIdx.x;
    const int lane = tid & 63;
    const int wave = tid >> 6;
    const int l15  = lane & 15;        // token within 16-tile
    const int lg   = lane >> 4;        // k-group (inputs) / j-quad (output)
    const int kb0  = lg * 8;
    const int tok_base = blockIdx.x * 128 + wave * 32;

    // ---- gather x fragments (MFMA B-operand): x = [E_w row | E_t row | pad] ----
    bf16x8 a[2][4];
    #pragma unroll
    for (int mt = 0; mt < 2; ++mt) {
        const int tok = tok_base + mt * 16 + l15;
        const float* ew = Ew + (size_t)sent[tok] * DW;
        const float* et = Et + (size_t)tags[tok] * DT;
        #pragma unroll
        for (int ks = 0; ks < 3; ++ks) {          // k in [0,96): pure E_w, 16B-aligned
            const float* p = ew + ks * 32 + kb0;
            const float4 v0 = *(const float4*)p;
            const float4 v1 = *(const float4*)(p + 4);
            bf16x8 f;
            f[0] = f2bf(v0.x); f[1] = f2bf(v0.y); f[2] = f2bf(v0.z); f[3] = f2bf(v0.w);
            f[4] = f2bf(v1.x); f[5] = f2bf(v1.y); f[6] = f2bf(v1.z); f[7] = f2bf(v1.w);
            a[mt][ks] = f;
        }
        {   // ks == 3: k in [96,128) -> E_w tail / E_t / zero pad
            float v[8];
            if (lg == 0) {
                const float4 w = *(const float4*)(ew + 96);
                v[0] = w.x; v[1] = w.y; v[2] = w.z; v[3] = w.w;
                #pragma unroll
                for (int e = 0; e < 4; ++e) v[4 + e] = et[e];
            } else {
                const int base = lg * 8 - 4;       // E_t index of elem 0
                #pragma unroll
                for (int e = 0; e < 8; ++e) {
                    const int ti = base + e;
                    v[e] = (ti < DT) ? et[ti] : 0.f;
                }
            }
            bf16x8 f;
            #pragma unroll
            for (int e = 0; e < 8; ++e) f[e] = f2bf(v[e]);
            a[mt][3] = f;
        }
    }

    float* hs = hstage[wave];

    // prologue: slab 0 (d=0, jt=0) into prefetch regs
    bf16x8 st[3];
    {
        const bf16x8* bp = bfrag + (size_t)(wave * 3) * 64 + lane;
        st[0] = bp[0]; st[1] = bp[64]; st[2] = bp[128];
    }

    for (int d = 0; d < 2; ++d) {
        for (int mt = 0; mt < 2; ++mt) {
            for (int jt = 0; jt < 7; ++jt) {
                const int q = (d * 2 + mt) * 7 + jt;   // phase 0..27
                __syncthreads();                       // A: prev slab readers done
                #pragma unroll
                for (int qq = 0; qq < 3; ++qq)
                    wbuf[(wave * 3 + qq) * 64 + lane] = st[qq];
                __syncthreads();                       // B: slab q ready

                // T14: issue next slab's global loads now (hide L2 latency)
                if (q < 27) {
                    const int qn  = q + 1;
                    const int sid = (qn / 14) * 7 + (qn % 7);   // (d,jt) of next phase
                    const bf16x8* bp = bfrag + ((size_t)sid * 12 + wave * 3) * 64 + lane;
                    st[0] = bp[0]; st[1] = bp[64]; st[2] = bp[128];
                }

                f32x4 acc[3];
                #pragma unroll
                for (int gt = 0; gt < 3; ++gt) {
                    // bias pre-folded into accumulator init (row = j = jt*16+lg*4+r)
                    acc[gt] = *(const f32x4*)&bias3[(size_t)(d * 3 + gt) * 112 + jt * 16 + lg * 4];
                    bf16x8 b[4];
                    #pragma unroll
                    for (int ks = 0; ks < 4; ++ks)
                        b[ks] = wbuf[(gt * 4 + ks) * 64 + lane];
                    #pragma unroll
                    for (int ks = 0; ks < 4; ++ks)
                        acc[gt] = __builtin_amdgcn_mfma_f32_16x16x32_bf16(
                            b[ks], a[mt][ks], acc[gt], 0, 0, 0);
                }

                const bool sv = (jt < 6) || (lg == 0);   // j-quad valid (j<100)
                if (sv) {
                    f32x4 h;
                    #pragma unroll
                    for (int r = 0; r < 4; ++r) {
                        const float c = sigm(acc[0][r]) * tanh_(acc[1][r]);
                        h[r] = sigm(acc[2][r]) * tanh_(c);
                    }
                    // packed staging: [token(16)][j(100)] f32
                    *(f32x4*)&hs[l15 * 100 + jt * 16 + lg * 4] = h;
                }

                if (jt == 6) {
                    // dense flush: 16 tokens x 400B contiguous per token
                    float* dst = out + (size_t)(tok_base + mt * 16) * 200 + d * 100;
                    #pragma unroll
                    for (int it = 0; it < 7; ++it) {
                        const int fd = it * 256 + lane * 4;     // dword offset, packed
                        if (fd < 1600) {
                            const int t = fd / 100;             // token (magic-mul)
                            const f32x4 v = *(const f32x4*)&hs[fd];
                            *(f32x4*)&dst[fd + t * 100] = v;    // = dst[t*200 + (fd - t*100)]
                        }
                    }
                }
            }
        }
    }
}

extern "C" void kernel_launch(void* const* d_in, const int* in_sizes, int n_in,
                              void* d_out, int out_size, void* d_ws, size_t ws_size,
                              hipStream_t stream) {
    (void)in_sizes; (void)n_in; (void)out_size; (void)ws_size;
    bf16x8* bfrag = (bf16x8*)d_ws;                       // 172032 B
    float*  bias3 = (float*)((char*)d_ws + 172032);      // 2688 B
    build_b<<<dim3(42), dim3(256), 0, stream>>>(
        (const float*)d_in[4], (const float*)d_in[5], (const float*)d_in[6],
        (const float*)d_in[7], (const float*)d_in[8], (const float*)d_in[9],
        bfrag, bias3);
    lstm_main<<<dim3(NTOK / 128), dim3(256), 0, stream>>>(
        (const int*)d_in[0], (const int*)d_in[1],
        (const float*)d_in[2], (const float*)d_in[3],
        bfrag, bias3, (float*)d_out);
}